// Round 6
// baseline (176.076 us; speedup 1.0000x reference)
//
#include <hip/hip_runtime.h>
#include <hip/hip_bf16.h>

// obs (4096,138) f32 | obstacles (4096,5,128) f32 | act (4096,2) f32
// ow1 (22,256) ob1(256) ow2 (256,256) ob2(256)
// qw1 (396,256) qb1(256) qw2 (256,256) qb2(256) qw3 (256,1) qb3(1)
// out: (4096,) f32

typedef __attribute__((ext_vector_type(8))) short short8;
typedef __attribute__((ext_vector_type(4))) float f32x4;

#define MFMA16(A, B, C) __builtin_amdgcn_mfma_f32_16x16x32_bf16(A, B, C, 0, 0, 0)

__device__ __forceinline__ unsigned short f2b(float f) {
  __hip_bfloat16 h = __float2bfloat16(f);
  return __builtin_bit_cast(unsigned short, h);
}
__device__ __forceinline__ float b2f(unsigned short u) {
  unsigned v = ((unsigned)u) << 16;
  return __builtin_bit_cast(float, v);
}
// fast pack: round-half-up (+0x8000) then take hi16 of both via one v_perm.
__device__ __forceinline__ unsigned pk2f(float a, float b) {
  unsigned ua = __builtin_bit_cast(unsigned, a) + 0x8000u;
  unsigned ub = __builtin_bit_cast(unsigned, b) + 0x8000u;
  return __builtin_amdgcn_perm(ub, ua, 0x07060302u);
}

// ---------------------------------------------------------------------------
// Kernel 0: pack weights (unchanged, 16x16x32 fragment layout everywhere).
// ---------------------------------------------------------------------------
__global__ __launch_bounds__(256) void pack_weights(
    const float* __restrict__ ow1, const float* __restrict__ ow2,
    const float* __restrict__ qw1, const float* __restrict__ qw2,
    unsigned short* __restrict__ ow1q, unsigned short* __restrict__ ow2p,
    unsigned short* __restrict__ qw1h, unsigned short* __restrict__ qw1l,
    unsigned short* __restrict__ qw2h, unsigned short* __restrict__ qw2l) {
  int i = blockIdx.x * 256 + threadIdx.x;  // 0..106495
  if (i < 8192) {
    int j = i & 7;
    int l15 = (i >> 3) & 15;
    int quad = (i >> 7) & 3;
    int mt = (i >> 9) & 15;
    int k = quad * 8 + j;
    float v = (k < 22) ? ow1[k * 256 + (mt * 16 + l15)] : 0.f;
    ow1q[i] = f2b(v);
  }
  if (i < 65536) {
    int j = i & 7;
    int n = (i >> 3) & 255;
    int qq = i >> 11;
    int k = (qq >> 2) * 32 + (qq & 3) * 8 + j;
    ow2p[i] = f2b(ow2[k * 256 + n]);
    float w = qw2[k * 256 + n];
    unsigned short h = f2b(w);
    qw2h[i] = h;
    qw2l[i] = f2b(w - b2f(h));
  }
  if (i < 106496) {
    int j = i & 7;
    int n = (i >> 3) & 255;
    int qq = i >> 11;  // 0..51 = kb*4+quad
    int k = (qq >> 2) * 32 + (qq & 3) * 8 + j;
    float w = (k < 396) ? qw1[k * 256 + n] : 0.f;
    unsigned short h = f2b(w);
    qw1h[i] = h;
    qw1l[i] = f2b(w - b2f(h));
  }
}

// ---------------------------------------------------------------------------
// Kernel 1 (RE-GANGED): HALF a batch element (64 rows) per block, 256
// threads (4 waves), 4 blocks/CU (LDS 40256B -> 40KB granule; 4x40 = 160KB).
// Same dense inner-loop structure as the proven r0/r4 kernel; per-wave L2
// tile is now (M64,N64): wave owns all 4 row-tiles and 4 n_out-tiles.
//   - 4 independent barrier-gangs per CU (was 2): phase overlap is the
//     target (no pipe was saturated: MFMA 40%, LDS 58%, L2 19%).
//   - A-LDS traffic per element halves (256KB); ow2p L2 traffic doubles
//     (headroom: L2 pipe was at 19%).
//   - Pool epilogue writes f32 PARTIALS to poolF[b][half][n]; head sums
//     the two halves (removes hi/lo pack VALU from this kernel).
// HSTR=272 kept: L2 A-read 16B-slot = (2*l15+quad) mod 32 = 2-way free.
// ---------------------------------------------------------------------------
#define XSTR 40   // xs row stride in shorts (x2B/16B = 5: conflict-free)
#define HSTR 272  // h1 row stride in shorts

__global__ __launch_bounds__(256, 4) void obstacle_kernel(
    const float* __restrict__ obs, const float* __restrict__ obstacles,
    const unsigned short* __restrict__ ow1q,
    const unsigned short* __restrict__ ow2p,
    const float* __restrict__ ob1, const float* __restrict__ ob2,
    float* __restrict__ poolF) {
  __shared__ __align__(16) unsigned short xs[64 * XSTR];  // 5120 B
  __shared__ __align__(16) unsigned short h1[64 * HSTR];  // 34816 B
  __shared__ float maskS[64];                             // 256 B
  __shared__ unsigned short vehB[32];                     // 64 B

  const int bb = blockIdx.x;          // 0..8191
  const int b = bb >> 1;              // batch element
  const int half = bb & 1;            // row half: rows half*64..+63
  const int tid = threadIdx.x;

  if (tid < 18) vehB[tid] = f2b(obs[b * 138 + tid]);
  if (tid < 64) maskS[tid] = obstacles[b * 640 + 512 + half * 64 + tid];
  __syncthreads();

  // Build x rows (2 threads per row, tid<128): [0:18]=veh, [18:22]=obst.
  if (tid < 128) {
    int n = tid >> 1;                 // local row 0..63
    int hf = tid & 1;
    unsigned short* wr = &xs[n * XSTR + hf * 16];
    if (hf == 0) {
      unsigned short r01[16];
#pragma unroll
      for (int k = 0; k < 16; k++) r01[k] = vehB[k];
      *(short8*)(wr + 0) = *(short8*)&r01[0];
      *(short8*)(wr + 8) = *(short8*)&r01[8];
    } else {
      unsigned short r2[8];
      r2[0] = vehB[16];
      r2[1] = vehB[17];
#pragma unroll
      for (int d = 0; d < 4; d++)
        r2[2 + d] = f2b(obstacles[b * 640 + d * 128 + half * 64 + n]);
      r2[6] = 0; r2[7] = 0;
      *(short8*)(wr + 0) = *(short8*)&r2[0];
      short8 z = {0, 0, 0, 0, 0, 0, 0, 0};
      *(short8*)(wr + 8) = z;
    }
  }
  __syncthreads();

  const int wave = tid >> 6;   // 0..3
  const int lane = tid & 63;
  const int quad = lane >> 4;
  const int l15 = lane & 15;

  // ---- Layer 1 (swapped, D = W1^T x X^T): wave owns 4 n_out tiles
  //      (wave*4+g), all 4 row tiles. Bias in C-init. ----
  {
    const unsigned short* wp = &ow1q[wave * 2048 + quad * 128 + l15 * 8];
    short8 wfr[4];
#pragma unroll
    for (int g = 0; g < 4; g++) wfr[g] = *(const short8*)(wp + g * 512);

    const unsigned short* bxp = &xs[l15 * XSTR + quad * 8];
    short8 bx[4];
#pragma unroll
    for (int mt = 0; mt < 4; mt++)
      bx[mt] = *(const short8*)(bxp + mt * 16 * XSTR);

    unsigned short* wrb = &h1[l15 * HSTR + wave * 64 + quad * 4];

#pragma unroll
    for (int g = 0; g < 4; g++) {
      f32x4 cinit = *(const f32x4*)&ob1[wave * 64 + g * 16 + quad * 4];
      f32x4 acc1[4];
#pragma unroll
      for (int mt = 0; mt < 4; mt++) acc1[mt] = MFMA16(wfr[g], bx[mt], cinit);
#pragma unroll
      for (int mt = 0; mt < 4; mt++) {
        float v0 = fmaxf(acc1[mt][0], 0.f);
        float v1 = fmaxf(acc1[mt][1], 0.f);
        float v2 = fmaxf(acc1[mt][2], 0.f);
        float v3 = fmaxf(acc1[mt][3], 0.f);
        uint2 pk;
        pk.x = pk2f(v0, v1);
        pk.y = pk2f(v2, v3);
        *(uint2*)(wrb + mt * 16 * HSTR + g * 16) = pk;
      }
    }
  }
  __syncthreads();

  // ---- Layer 2: wave owns ALL 4 mt, nt = wave*4..+3 (B reuse 4, A reuse
  //      4); bias in C-init; B prefetched one kb ahead. 16 MFMA per kb. ----
  f32x4 acc[4][4];             // [mt][t]
#pragma unroll
  for (int t = 0; t < 4; t++) {
    float bv = ob2[wave * 64 + t * 16 + l15];
    f32x4 bvec = {bv, bv, bv, bv};
#pragma unroll
    for (int mt = 0; mt < 4; mt++) acc[mt][t] = bvec;
  }

  const unsigned short* bp = &ow2p[(quad * 256 + wave * 64 + l15) * 8];
  const unsigned short* h1r = &h1[l15 * HSTR + quad * 8];
  short8 bcur[4], bnxt[4];
#pragma unroll
  for (int t = 0; t < 4; t++) bcur[t] = *(const short8*)(bp + t * 128);

#pragma unroll 1
  for (int kb = 0; kb < 8; kb++) {
    if (kb < 7) {
#pragma unroll
      for (int t = 0; t < 4; t++)
        bnxt[t] = *(const short8*)(bp + 8192 + t * 128);
    }
    short8 afr[4];
#pragma unroll
    for (int mt = 0; mt < 4; mt++)
      afr[mt] = *(const short8*)(h1r + mt * 16 * HSTR);
#pragma unroll
    for (int mt = 0; mt < 4; mt++)
#pragma unroll
      for (int t = 0; t < 4; t++) acc[mt][t] = MFMA16(afr[mt], bcur[t], acc[mt][t]);
    bp += 8192;
    h1r += 32;
    if (kb < 7) {
#pragma unroll
      for (int t = 0; t < 4; t++) bcur[t] = bnxt[t];
    }
  }

  // ---- Pool epilogue: PARTIAL pooled over this half's 64 rows:
  //      poolF[b*512 + half*256 + n] = sum_m mask[m]*relu(h2[m][n]). ----
  f32x4 mk[4];
  const float* mkp = &maskS[quad * 4];
#pragma unroll
  for (int mt = 0; mt < 4; mt++) mk[mt] = *(const f32x4*)(mkp + mt * 16);

#pragma unroll
  for (int t = 0; t < 4; t++) {
    float s = 0.f;
#pragma unroll
    for (int mt = 0; mt < 4; mt++) {
#pragma unroll
      for (int r = 0; r < 4; r++) {
        float v = fmaxf(acc[mt][t][r], 0.f);
        s = fmaf(mk[mt][r], v, s);
      }
    }
    s += __shfl_xor(s, 16);
    s += __shfl_xor(s, 32);
    if (quad == 0) {
      int n = wave * 64 + t * 16 + l15;
      poolF[b * 512 + half * 256 + n] = s;
    }
  }
}

// ---------------------------------------------------------------------------
// Kernel 2: head MLP via MFMA, hi/lo bf16 split (3-term). 256 blocks x 1024
// threads. Round-5 structure; comb build now sums the two f32 pool
// partials and does the hi/lo split here.
// ---------------------------------------------------------------------------
__global__ __launch_bounds__(1024) void head_mfma(
    const float* __restrict__ obs, const float* __restrict__ act,
    const float* __restrict__ poolF,
    const unsigned short* __restrict__ qw1h,
    const unsigned short* __restrict__ qw1l,
    const unsigned short* __restrict__ qw2h,
    const unsigned short* __restrict__ qw2l,
    const float* __restrict__ qb1, const float* __restrict__ qb2,
    const float* __restrict__ qw3, const float* __restrict__ qb3,
    float* __restrict__ out) {
  const int CSTR = 424;
  const int HSTRQ = 272;
  __shared__ unsigned short combH[16 * 424], combL[16 * 424];
  __shared__ unsigned short h1H[16 * 272], h1L[16 * 272];
  __shared__ float wred[16][16];

  const int tid = threadIdx.x;
  const int r0 = blockIdx.x * 16;
  const int wave = tid >> 6;  // 0..15 = N-tile
  const int lane = tid & 63;
  const int quad = lane >> 4;
  const int l15 = lane & 15;
  const int n = wave * 16 + l15;

  // Weight fragment bases: off(kb) = kb*8192 + (quad*256+n)*8.
  const unsigned short* w1h = &qw1h[(quad * 256 + n) * 8];
  const unsigned short* w1l = &qw1l[(quad * 256 + n) * 8];
  const unsigned short* w2h = &qw2h[(quad * 256 + n) * 8];
  const unsigned short* w2l = &qw2l[(quad * 256 + n) * 8];

  // Prefetch L1 kb=0,1 before the barrier: in flight across comb build.
  short8 bh[2], bl[2];
  bh[0] = *(const short8*)(w1h);
  bl[0] = *(const short8*)(w1l);
  bh[1] = *(const short8*)(w1h + 8192);
  bl[1] = *(const short8*)(w1l + 8192);

  // Build comb hi/lo: [obs(138) | pooled(256) | act(2) | pad->416]
  for (int idx = tid; idx < 16 * 416; idx += 1024) {
    int m = idx / 416;
    int k = idx - m * 416;
    unsigned short hi, lo;
    if (k < 138) {
      float v = obs[(r0 + m) * 138 + k];
      hi = f2b(v);
      lo = f2b(v - b2f(hi));
    } else if (k < 394) {
      float v = poolF[(r0 + m) * 512 + (k - 138)] +
                poolF[(r0 + m) * 512 + 256 + (k - 138)];
      hi = f2b(v);
      lo = f2b(v - b2f(hi));
    } else if (k < 396) {
      float v = act[(r0 + m) * 2 + (k - 394)];
      hi = f2b(v);
      lo = f2b(v - b2f(hi));
    } else {
      hi = 0; lo = 0;
    }
    combH[m * CSTR + k] = hi;
    combL[m * CSTR + k] = lo;
  }
  __syncthreads();

  // ---- Layer 1: 13 kb, fully unrolled, weights prefetched 2 ahead ----
  f32x4 acc = {0.f, 0.f, 0.f, 0.f}, accm = {0.f, 0.f, 0.f, 0.f};
#pragma unroll
  for (int kb = 0; kb < 13; kb++) {
    const int c = kb & 1;
    short8 ch = bh[c];
    short8 cl = bl[c];
    if (kb + 2 < 13) {
      bh[c] = *(const short8*)(w1h + (kb + 2) * 8192);
      bl[c] = *(const short8*)(w1l + (kb + 2) * 8192);
    }
    int ao = l15 * CSTR + kb * 32 + quad * 8;
    short8 ah = *(const short8*)&combH[ao];
    short8 al = *(const short8*)&combL[ao];
    acc = MFMA16(ah, ch, acc);
    accm = MFMA16(ah, cl, accm);
    accm = MFMA16(al, ch, accm);
  }
  {
    float bias = qb1[n];
#pragma unroll
    for (int r = 0; r < 4; r++) {
      int m = quad * 4 + r;
      float v = fmaxf(acc[r] + accm[r] + bias, 0.f);
      unsigned short hi = f2b(v);
      h1H[m * HSTRQ + n] = hi;
      h1L[m * HSTRQ + n] = f2b(v - b2f(hi));
    }
  }

  // Prefetch L2 kb=0,1 here: bh/bl are dead, loads ride across the barrier.
  short8 dh[2], dl[2];
  dh[0] = *(const short8*)(w2h);
  dl[0] = *(const short8*)(w2l);
  dh[1] = *(const short8*)(w2h + 8192);
  dl[1] = *(const short8*)(w2l + 8192);

  __syncthreads();

  // ---- Layer 2: 8 kb, fully unrolled, weights prefetched 2 ahead ----
  f32x4 a2 = {0.f, 0.f, 0.f, 0.f}, a2m = {0.f, 0.f, 0.f, 0.f};
#pragma unroll
  for (int kb = 0; kb < 8; kb++) {
    const int c = kb & 1;
    short8 ch = dh[c];
    short8 cl = dl[c];
    if (kb + 2 < 8) {
      dh[c] = *(const short8*)(w2h + (kb + 2) * 8192);
      dl[c] = *(const short8*)(w2l + (kb + 2) * 8192);
    }
    int ao = l15 * HSTRQ + kb * 32 + quad * 8;
    short8 ah = *(const short8*)&h1H[ao];
    short8 al = *(const short8*)&h1L[ao];
    a2 = MFMA16(ah, ch, a2);
    a2m = MFMA16(ah, cl, a2m);
    a2m = MFMA16(al, ch, a2m);
  }

  // ---- Layer 3: f32 dot with qw3, reduce over the wave's 16 cols ----
  {
    float w3 = qw3[n];
    float qb2n = qb2[n];
#pragma unroll
    for (int r = 0; r < 4; r++) {
      float v = fmaxf(a2[r] + a2m[r] + qb2n, 0.f);
      float s = v * w3;
      s += __shfl_xor(s, 1);
      s += __shfl_xor(s, 2);
      s += __shfl_xor(s, 4);
      s += __shfl_xor(s, 8);
      if (l15 == 0) wred[wave][quad * 4 + r] = s;
    }
  }
  __syncthreads();
  if (tid < 16) {
    float s = qb3[0];
#pragma unroll
    for (int w = 0; w < 16; w++) s += wred[w][tid];
    out[r0 + tid] = s;
  }
}

// ---------------------------------------------------------------------------
extern "C" void kernel_launch(void* const* d_in, const int* in_sizes, int n_in,
                              void* d_out, int out_size, void* d_ws, size_t ws_size,
                              hipStream_t stream) {
  const float* obs       = (const float*)d_in[0];
  const float* obstacles = (const float*)d_in[1];
  const float* act       = (const float*)d_in[2];
  const float* ow1       = (const float*)d_in[3];
  const float* ob1       = (const float*)d_in[4];
  const float* ow2       = (const float*)d_in[5];
  const float* ob2       = (const float*)d_in[6];
  const float* qw1       = (const float*)d_in[7];
  const float* qb1       = (const float*)d_in[8];
  const float* qw2       = (const float*)d_in[9];
  const float* qb2       = (const float*)d_in[10];
  const float* qw3       = (const float*)d_in[11];
  const float* qb3       = (const float*)d_in[12];
  float* out = (float*)d_out;

  unsigned short* ow1q = (unsigned short*)d_ws;   // 8192
  unsigned short* ow2p = ow1q + 8192;             // 65536
  unsigned short* qw1h = ow2p + 65536;            // 106496
  unsigned short* qw1l = qw1h + 106496;           // 106496
  unsigned short* qw2h = qw1l + 106496;           // 65536
  unsigned short* qw2l = qw2h + 65536;            // 65536
  float* poolF = (float*)(qw2l + 65536);          // 4096*512 f32 = 8MB

  pack_weights<<<416, 256, 0, stream>>>(ow1, ow2, qw1, qw2, ow1q, ow2p, qw1h,
                                        qw1l, qw2h, qw2l);
  obstacle_kernel<<<8192, 256, 0, stream>>>(obs, obstacles, ow1q, ow2p, ob1,
                                            ob2, poolF);
  head_mfma<<<256, 1024, 0, stream>>>(obs, act, poolF, qw1h, qw1l,
                                      qw2h, qw2l, qb1, qb2, qw3, qb3, out);
}

// Round 7
// 172.705 us; speedup vs baseline: 1.0195x; 1.0195x over previous
//
#include <hip/hip_runtime.h>
#include <hip/hip_bf16.h>

// obs (4096,138) f32 | obstacles (4096,5,128) f32 | act (4096,2) f32
// ow1 (22,256) ob1(256) ow2 (256,256) ob2(256)
// qw1 (396,256) qb1(256) qw2 (256,256) qb2(256) qw3 (256,1) qb3(1)
// out: (4096,) f32

typedef __attribute__((ext_vector_type(8))) short short8;
typedef __attribute__((ext_vector_type(4))) float f32x4;

#define MFMA16(A, B, C) __builtin_amdgcn_mfma_f32_16x16x32_bf16(A, B, C, 0, 0, 0)

__device__ __forceinline__ unsigned short f2b(float f) {
  __hip_bfloat16 h = __float2bfloat16(f);
  return __builtin_bit_cast(unsigned short, h);
}
__device__ __forceinline__ float b2f(unsigned short u) {
  unsigned v = ((unsigned)u) << 16;
  return __builtin_bit_cast(float, v);
}
// fast pack: round-half-up (+0x8000) then take hi16 of both via one v_perm.
__device__ __forceinline__ unsigned pk2f(float a, float b) {
  unsigned ua = __builtin_bit_cast(unsigned, a) + 0x8000u;
  unsigned ub = __builtin_bit_cast(unsigned, b) + 0x8000u;
  return __builtin_amdgcn_perm(ub, ua, 0x07060302u);
}

// ---------------------------------------------------------------------------
// Kernel 0: pack weights (r4 version, unchanged).
// ---------------------------------------------------------------------------
__global__ __launch_bounds__(256) void pack_weights(
    const float* __restrict__ ow1, const float* __restrict__ ow2,
    const float* __restrict__ qw1, const float* __restrict__ qw2,
    unsigned short* __restrict__ ow1q, unsigned short* __restrict__ ow2p,
    unsigned short* __restrict__ qw1h, unsigned short* __restrict__ qw1l,
    unsigned short* __restrict__ qw2h, unsigned short* __restrict__ qw2l) {
  int i = blockIdx.x * 256 + threadIdx.x;  // 0..106495
  if (i < 8192) {
    int j = i & 7;
    int l15 = (i >> 3) & 15;
    int quad = (i >> 7) & 3;
    int mt = (i >> 9) & 15;
    int k = quad * 8 + j;
    float v = (k < 22) ? ow1[k * 256 + (mt * 16 + l15)] : 0.f;
    ow1q[i] = f2b(v);
  }
  if (i < 65536) {
    int j = i & 7;
    int n = (i >> 3) & 255;
    int qq = i >> 11;
    int k = (qq >> 2) * 32 + (qq & 3) * 8 + j;
    ow2p[i] = f2b(ow2[k * 256 + n]);
    float w = qw2[k * 256 + n];
    unsigned short h = f2b(w);
    qw2h[i] = h;
    qw2l[i] = f2b(w - b2f(h));
  }
  if (i < 106496) {
    int j = i & 7;
    int n = (i >> 3) & 255;
    int qq = i >> 11;  // 0..51 = kb*4+quad
    int k = (qq >> 2) * 32 + (qq & 3) * 8 + j;
    float w = (k < 396) ? qw1[k * 256 + n] : 0.f;
    unsigned short h = f2b(w);
    qw1h[i] = h;
    qw1l[i] = f2b(w - b2f(h));
  }
}

// ---------------------------------------------------------------------------
// Kernel 1: BYTE-IDENTICAL to round-4 (best measured: ~82us obstacle).
// Full 128-row batch element per block, 512 threads (8 waves), 2 blocks/CU.
// HSTR=272: layer-2 A-read slot map (2*l15+quad) = uniform 2-way (free).
// ---------------------------------------------------------------------------
#define XSTR 40   // xs row stride in shorts (x2B/16B = 5: conflict-free)
#define HSTR 272  // h1 row stride in shorts

__global__ __launch_bounds__(512, 4) void obstacle_kernel(
    const float* __restrict__ obs, const float* __restrict__ obstacles,
    const unsigned short* __restrict__ ow1q,
    const unsigned short* __restrict__ ow2p,
    const float* __restrict__ ob1, const float* __restrict__ ob2,
    unsigned short* __restrict__ poolH, unsigned short* __restrict__ poolL) {
  __shared__ __align__(16) unsigned short xs[128 * XSTR];  // 10240 B
  __shared__ __align__(16) unsigned short h1[128 * HSTR];  // 69632 B
  __shared__ float maskS[128];
  __shared__ unsigned short vehB[32];

  const int b = blockIdx.x;
  const int tid = threadIdx.x;

  if (tid < 18) vehB[tid] = f2b(obs[b * 138 + tid]);
  if (tid < 128) maskS[tid] = obstacles[b * 640 + 512 + tid];
  __syncthreads();

  // Build x rows (2 threads per row, tid<256): [0:18]=veh, [18:22]=obst.
  if (tid < 256) {
    int n = tid >> 1;
    int half = tid & 1;
    unsigned short* wr = &xs[n * XSTR + half * 16];
    if (half == 0) {
      unsigned short r01[16];
#pragma unroll
      for (int k = 0; k < 16; k++) r01[k] = vehB[k];
      *(short8*)(wr + 0) = *(short8*)&r01[0];
      *(short8*)(wr + 8) = *(short8*)&r01[8];
    } else {
      unsigned short r2[8];
      r2[0] = vehB[16];
      r2[1] = vehB[17];
#pragma unroll
      for (int d = 0; d < 4; d++)
        r2[2 + d] = f2b(obstacles[b * 640 + d * 128 + n]);
      r2[6] = 0; r2[7] = 0;
      *(short8*)(wr + 0) = *(short8*)&r2[0];
      short8 z = {0, 0, 0, 0, 0, 0, 0, 0};
      *(short8*)(wr + 8) = z;
    }
  }
  __syncthreads();

  const int wave = tid >> 6;   // 0..7
  const int lane = tid & 63;
  const int quad = lane >> 4;
  const int l15 = lane & 15;

  // ---- Layer 1 (swapped, D = W1^T x X^T): wave owns 2 n_out tiles
  //      (wave*2, wave*2+1), all 8 row tiles. Bias in C-init. ----
  {
    const unsigned short* wp = &ow1q[wave * 1024 + quad * 128 + l15 * 8];
    short8 wfr[2];
#pragma unroll
    for (int i = 0; i < 2; i++) wfr[i] = *(const short8*)(wp + i * 512);

    const unsigned short* bxp = &xs[l15 * XSTR + quad * 8];
    short8 bx[8];
#pragma unroll
    for (int nt = 0; nt < 8; nt++)
      bx[nt] = *(const short8*)(bxp + nt * 16 * XSTR);

    unsigned short* wrb = &h1[l15 * HSTR + wave * 32 + quad * 4];

#pragma unroll
    for (int i = 0; i < 2; i++) {
      f32x4 cinit = *(const f32x4*)&ob1[wave * 32 + i * 16 + quad * 4];
      f32x4 acc1[8];
#pragma unroll
      for (int nt = 0; nt < 8; nt++) acc1[nt] = MFMA16(wfr[i], bx[nt], cinit);
#pragma unroll
      for (int nt = 0; nt < 8; nt++) {
        float v0 = fmaxf(acc1[nt][0], 0.f);
        float v1 = fmaxf(acc1[nt][1], 0.f);
        float v2 = fmaxf(acc1[nt][2], 0.f);
        float v3 = fmaxf(acc1[nt][3], 0.f);
        uint2 pk;
        pk.x = pk2f(v0, v1);
        pk.y = pk2f(v2, v3);
        *(uint2*)(wrb + nt * 16 * HSTR + i * 16) = pk;
      }
    }
  }
  __syncthreads();

  // ---- Layer 2: wave owns ALL 8 mt, nt = wave*2..+1 (B reuse 8);
  //      bias in C-init; B prefetched one kb ahead. ----
  f32x4 acc[8][2];
#pragma unroll
  for (int t = 0; t < 2; t++) {
    float bv = ob2[wave * 32 + t * 16 + l15];
    f32x4 bvec = {bv, bv, bv, bv};
#pragma unroll
    for (int mt = 0; mt < 8; mt++) acc[mt][t] = bvec;
  }

  const unsigned short* bp = &ow2p[(quad * 256 + wave * 32 + l15) * 8];
  const unsigned short* h1r = &h1[l15 * HSTR + quad * 8];
  short8 bcur[2], bnxt[2];
#pragma unroll
  for (int t = 0; t < 2; t++) bcur[t] = *(const short8*)(bp + t * 128);

#pragma unroll 1
  for (int kb = 0; kb < 8; kb++) {
    if (kb < 7) {
#pragma unroll
      for (int t = 0; t < 2; t++)
        bnxt[t] = *(const short8*)(bp + 8192 + t * 128);
    }
    short8 afr[8];
#pragma unroll
    for (int mt = 0; mt < 8; mt++)
      afr[mt] = *(const short8*)(h1r + mt * 16 * HSTR);
#pragma unroll
    for (int mt = 0; mt < 8; mt++)
#pragma unroll
      for (int t = 0; t < 2; t++) acc[mt][t] = MFMA16(afr[mt], bcur[t], acc[mt][t]);
    bp += 8192;
    h1r += 32;
    if (kb < 7) {
#pragma unroll
      for (int t = 0; t < 2; t++) bcur[t] = bnxt[t];
    }
  }

  // ---- Pool epilogue: pooled[n] = sum_m mask[m]*relu(h2[m][n]);
  //      column n owned by exactly one wave. ----
  f32x4 mk[8];
  const float* mkp = &maskS[quad * 4];
#pragma unroll
  for (int mt = 0; mt < 8; mt++) mk[mt] = *(const f32x4*)(mkp + mt * 16);

#pragma unroll
  for (int t = 0; t < 2; t++) {
    float s = 0.f;
#pragma unroll
    for (int mt = 0; mt < 8; mt++) {
#pragma unroll
      for (int r = 0; r < 4; r++) {
        float v = fmaxf(acc[mt][t][r], 0.f);
        s = fmaf(mk[mt][r], v, s);
      }
    }
    s += __shfl_xor(s, 16);
    s += __shfl_xor(s, 32);
    if (quad == 0) {
      int n = wave * 32 + t * 16 + l15;
      unsigned short sh = (unsigned short)(__builtin_bit_cast(unsigned, s) >> 16);
      poolH[b * 256 + n] = sh;  // truncated hi; lo captures remainder
      poolL[b * 256 + n] = f2b(s - b2f(sh));
    }
  }
}

// ---------------------------------------------------------------------------
// Kernel 2 (RE-GANGED): head MLP, hi/lo bf16 split (3-term).
// 512 blocks x 512 threads, 8 ROWS per block -> 2 blocks/CU (2 barrier
// gangs, 16 waves/CU) instead of 256x1024 (1 gang/CU, all phases serial).
// Rows 8..15 of comb are zero-padded (their outputs are discarded).
// 8 waves; wave owns 2 N-tiles (n = wave*32 + t*16 + l15).
// LDS ~46KB/block -> 2 blocks/CU fits (160KB).
// ---------------------------------------------------------------------------
__global__ __launch_bounds__(512) void head_mfma(
    const float* __restrict__ obs, const float* __restrict__ act,
    const unsigned short* __restrict__ poolH,
    const unsigned short* __restrict__ poolL,
    const unsigned short* __restrict__ qw1h,
    const unsigned short* __restrict__ qw1l,
    const unsigned short* __restrict__ qw2h,
    const unsigned short* __restrict__ qw2l,
    const float* __restrict__ qb1, const float* __restrict__ qb2,
    const float* __restrict__ qw3, const float* __restrict__ qb3,
    float* __restrict__ out) {
  const int CSTR = 424;
  const int HSTRQ = 272;
  __shared__ unsigned short combH[16 * 424], combL[16 * 424];
  __shared__ unsigned short h1H[16 * 272], h1L[16 * 272];
  __shared__ float wred[16][16];

  const int tid = threadIdx.x;
  const int r0 = blockIdx.x * 8;
  const int wave = tid >> 6;  // 0..7
  const int lane = tid & 63;
  const int quad = lane >> 4;
  const int l15 = lane & 15;
  const int n0 = wave * 32 + l15;        // t=0 column
  const int n1 = wave * 32 + 16 + l15;   // t=1 column

  // Weight fragment bases: off(kb) = kb*8192 + (quad*256+n)*8.
  const unsigned short* w1h0 = &qw1h[(quad * 256 + n0) * 8];
  const unsigned short* w1l0 = &qw1l[(quad * 256 + n0) * 8];
  const unsigned short* w1h1 = &qw1h[(quad * 256 + n1) * 8];
  const unsigned short* w1l1 = &qw1l[(quad * 256 + n1) * 8];

  // Prefetch L1 kb=0,1 for both tiles before the barrier.
  short8 bh0[2], bl0[2], bh1[2], bl1[2];
  bh0[0] = *(const short8*)(w1h0);
  bl0[0] = *(const short8*)(w1l0);
  bh0[1] = *(const short8*)(w1h0 + 8192);
  bl0[1] = *(const short8*)(w1l0 + 8192);
  bh1[0] = *(const short8*)(w1h1);
  bl1[0] = *(const short8*)(w1l1);
  bh1[1] = *(const short8*)(w1h1 + 8192);
  bl1[1] = *(const short8*)(w1l1 + 8192);

  // Build comb hi/lo: rows 0..7 = batch rows r0..r0+7; rows 8..15 = zero.
  for (int idx = tid; idx < 16 * 416; idx += 512) {
    int m = idx / 416;
    int k = idx - m * 416;
    unsigned short hi = 0, lo = 0;
    if (m < 8) {
      if (k < 138) {
        float v = obs[(r0 + m) * 138 + k];
        hi = f2b(v);
        lo = f2b(v - b2f(hi));
      } else if (k < 394) {
        hi = poolH[(r0 + m) * 256 + (k - 138)];
        lo = poolL[(r0 + m) * 256 + (k - 138)];
      } else if (k < 396) {
        float v = act[(r0 + m) * 2 + (k - 394)];
        hi = f2b(v);
        lo = f2b(v - b2f(hi));
      }
    }
    combH[m * CSTR + k] = hi;
    combL[m * CSTR + k] = lo;
  }
  __syncthreads();

  // ---- Layer 1: 13 kb, fully unrolled, weights prefetched 2 ahead.
  //      One comb read pair feeds both N-tiles (6 MFMAs). ----
  f32x4 acc0 = {0.f, 0.f, 0.f, 0.f}, accm0 = {0.f, 0.f, 0.f, 0.f};
  f32x4 acc1 = {0.f, 0.f, 0.f, 0.f}, accm1 = {0.f, 0.f, 0.f, 0.f};
#pragma unroll
  for (int kb = 0; kb < 13; kb++) {
    const int c = kb & 1;
    short8 ch0 = bh0[c], cl0 = bl0[c];
    short8 ch1 = bh1[c], cl1 = bl1[c];
    if (kb + 2 < 13) {
      bh0[c] = *(const short8*)(w1h0 + (kb + 2) * 8192);
      bl0[c] = *(const short8*)(w1l0 + (kb + 2) * 8192);
      bh1[c] = *(const short8*)(w1h1 + (kb + 2) * 8192);
      bl1[c] = *(const short8*)(w1l1 + (kb + 2) * 8192);
    }
    int ao = l15 * CSTR + kb * 32 + quad * 8;
    short8 ah = *(const short8*)&combH[ao];
    short8 al = *(const short8*)&combL[ao];
    acc0 = MFMA16(ah, ch0, acc0);
    accm0 = MFMA16(ah, cl0, accm0);
    accm0 = MFMA16(al, ch0, accm0);
    acc1 = MFMA16(ah, ch1, acc1);
    accm1 = MFMA16(ah, cl1, accm1);
    accm1 = MFMA16(al, ch1, accm1);
  }
  {
    float bias0 = qb1[n0];
    float bias1 = qb1[n1];
#pragma unroll
    for (int r = 0; r < 4; r++) {
      int m = quad * 4 + r;
      float v0 = fmaxf(acc0[r] + accm0[r] + bias0, 0.f);
      unsigned short hi0 = f2b(v0);
      h1H[m * HSTRQ + n0] = hi0;
      h1L[m * HSTRQ + n0] = f2b(v0 - b2f(hi0));
      float v1 = fmaxf(acc1[r] + accm1[r] + bias1, 0.f);
      unsigned short hi1 = f2b(v1);
      h1H[m * HSTRQ + n1] = hi1;
      h1L[m * HSTRQ + n1] = f2b(v1 - b2f(hi1));
    }
  }

  // Prefetch L2 kb=0,1 (registers of L1 weight bufs are dead here).
  const unsigned short* w2h0 = &qw2h[(quad * 256 + n0) * 8];
  const unsigned short* w2l0 = &qw2l[(quad * 256 + n0) * 8];
  const unsigned short* w2h1 = &qw2h[(quad * 256 + n1) * 8];
  const unsigned short* w2l1 = &qw2l[(quad * 256 + n1) * 8];
  short8 dh0[2], dl0[2], dh1[2], dl1[2];
  dh0[0] = *(const short8*)(w2h0);
  dl0[0] = *(const short8*)(w2l0);
  dh0[1] = *(const short8*)(w2h0 + 8192);
  dl0[1] = *(const short8*)(w2l0 + 8192);
  dh1[0] = *(const short8*)(w2h1);
  dl1[0] = *(const short8*)(w2l1);
  dh1[1] = *(const short8*)(w2h1 + 8192);
  dl1[1] = *(const short8*)(w2l1 + 8192);

  __syncthreads();

  // ---- Layer 2: 8 kb, fully unrolled, weights prefetched 2 ahead ----
  f32x4 a20 = {0.f, 0.f, 0.f, 0.f}, a2m0 = {0.f, 0.f, 0.f, 0.f};
  f32x4 a21 = {0.f, 0.f, 0.f, 0.f}, a2m1 = {0.f, 0.f, 0.f, 0.f};
#pragma unroll
  for (int kb = 0; kb < 8; kb++) {
    const int c = kb & 1;
    short8 ch0 = dh0[c], cl0 = dl0[c];
    short8 ch1 = dh1[c], cl1 = dl1[c];
    if (kb + 2 < 8) {
      dh0[c] = *(const short8*)(w2h0 + (kb + 2) * 8192);
      dl0[c] = *(const short8*)(w2l0 + (kb + 2) * 8192);
      dh1[c] = *(const short8*)(w2h1 + (kb + 2) * 8192);
      dl1[c] = *(const short8*)(w2l1 + (kb + 2) * 8192);
    }
    int ao = l15 * HSTRQ + kb * 32 + quad * 8;
    short8 ah = *(const short8*)&h1H[ao];
    short8 al = *(const short8*)&h1L[ao];
    a20 = MFMA16(ah, ch0, a20);
    a2m0 = MFMA16(ah, cl0, a2m0);
    a2m0 = MFMA16(al, ch0, a2m0);
    a21 = MFMA16(ah, ch1, a21);
    a2m1 = MFMA16(ah, cl1, a2m1);
    a2m1 = MFMA16(al, ch1, a2m1);
  }

  // ---- Layer 3: f32 dot with qw3, reduce over each tile's 16 cols ----
  {
    float w30 = qw3[n0], w31 = qw3[n1];
    float qb20 = qb2[n0], qb21 = qb2[n1];
#pragma unroll
    for (int r = 0; r < 4; r++) {
      float v0 = fmaxf(a20[r] + a2m0[r] + qb20, 0.f);
      float s0 = v0 * w30;
      s0 += __shfl_xor(s0, 1);
      s0 += __shfl_xor(s0, 2);
      s0 += __shfl_xor(s0, 4);
      s0 += __shfl_xor(s0, 8);
      float v1 = fmaxf(a21[r] + a2m1[r] + qb21, 0.f);
      float s1 = v1 * w31;
      s1 += __shfl_xor(s1, 1);
      s1 += __shfl_xor(s1, 2);
      s1 += __shfl_xor(s1, 4);
      s1 += __shfl_xor(s1, 8);
      if (l15 == 0) {
        wred[wave * 2 + 0][quad * 4 + r] = s0;
        wred[wave * 2 + 1][quad * 4 + r] = s1;
      }
    }
  }
  __syncthreads();
  if (tid < 8) {
    float s = qb3[0];
#pragma unroll
    for (int w = 0; w < 16; w++) s += wred[w][tid];
    out[r0 + tid] = s;
  }
}

// ---------------------------------------------------------------------------
extern "C" void kernel_launch(void* const* d_in, const int* in_sizes, int n_in,
                              void* d_out, int out_size, void* d_ws, size_t ws_size,
                              hipStream_t stream) {
  const float* obs       = (const float*)d_in[0];
  const float* obstacles = (const float*)d_in[1];
  const float* act       = (const float*)d_in[2];
  const float* ow1       = (const float*)d_in[3];
  const float* ob1       = (const float*)d_in[4];
  const float* ow2       = (const float*)d_in[5];
  const float* ob2       = (const float*)d_in[6];
  const float* qw1       = (const float*)d_in[7];
  const float* qb1       = (const float*)d_in[8];
  const float* qw2       = (const float*)d_in[9];
  const float* qb2       = (const float*)d_in[10];
  const float* qw3       = (const float*)d_in[11];
  const float* qb3       = (const float*)d_in[12];
  float* out = (float*)d_out;

  unsigned short* ow1q = (unsigned short*)d_ws;   // 8192
  unsigned short* ow2p = ow1q + 8192;             // 65536
  unsigned short* qw1h = ow2p + 65536;            // 106496
  unsigned short* qw1l = qw1h + 106496;           // 106496
  unsigned short* qw2h = qw1l + 106496;           // 65536
  unsigned short* qw2l = qw2h + 65536;            // 65536
  unsigned short* poolH = qw2l + 65536;           // 4096*256
  unsigned short* poolL = poolH + 1048576;        // 4096*256

  pack_weights<<<416, 256, 0, stream>>>(ow1, ow2, qw1, qw2, ow1q, ow2p, qw1h,
                                        qw1l, qw2h, qw2l);
  obstacle_kernel<<<4096, 512, 0, stream>>>(obs, obstacles, ow1q, ow2p, ob1,
                                            ob2, poolH, poolL);
  head_mfma<<<512, 512, 0, stream>>>(obs, act, poolH, poolL, qw1h, qw1l,
                                     qw2h, qw2l, qb1, qb2, qw3, qb3, out);
}

// Round 8
// 172.622 us; speedup vs baseline: 1.0200x; 1.0005x over previous
//
#include <hip/hip_runtime.h>
#include <hip/hip_bf16.h>

// obs (4096,138) f32 | obstacles (4096,5,128) f32 | act (4096,2) f32
// ow1 (22,256) ob1(256) ow2 (256,256) ob2(256)
// qw1 (396,256) qb1(256) qw2 (256,256) qb2(256) qw3 (256,1) qb3(1)
// out: (4096,) f32

typedef __attribute__((ext_vector_type(8))) short short8;
typedef __attribute__((ext_vector_type(4))) float f32x4;

#define MFMA16(A, B, C) __builtin_amdgcn_mfma_f32_16x16x32_bf16(A, B, C, 0, 0, 0)

__device__ __forceinline__ unsigned short f2b(float f) {
  __hip_bfloat16 h = __float2bfloat16(f);
  return __builtin_bit_cast(unsigned short, h);
}
__device__ __forceinline__ float b2f(unsigned short u) {
  unsigned v = ((unsigned)u) << 16;
  return __builtin_bit_cast(float, v);
}
// fast pack: round-half-up (+0x8000) then take hi16 of both via one v_perm.
__device__ __forceinline__ unsigned pk2f(float a, float b) {
  unsigned ua = __builtin_bit_cast(unsigned, a) + 0x8000u;
  unsigned ub = __builtin_bit_cast(unsigned, b) + 0x8000u;
  return __builtin_amdgcn_perm(ub, ua, 0x07060302u);
}

// ---------------------------------------------------------------------------
// Kernel 0: pack weights (byte-identical to the 166.2us config).
// ---------------------------------------------------------------------------
__global__ __launch_bounds__(256) void pack_weights(
    const float* __restrict__ ow1, const float* __restrict__ ow2,
    const float* __restrict__ qw1, const float* __restrict__ qw2,
    unsigned short* __restrict__ ow1q, unsigned short* __restrict__ ow2p,
    unsigned short* __restrict__ qw1h, unsigned short* __restrict__ qw1l,
    unsigned short* __restrict__ qw2h, unsigned short* __restrict__ qw2l) {
  int i = blockIdx.x * 256 + threadIdx.x;  // 0..106495
  if (i < 8192) {
    int j = i & 7;
    int l15 = (i >> 3) & 15;
    int quad = (i >> 7) & 3;
    int mt = (i >> 9) & 15;
    int k = quad * 8 + j;
    float v = (k < 22) ? ow1[k * 256 + (mt * 16 + l15)] : 0.f;
    ow1q[i] = f2b(v);
  }
  if (i < 65536) {
    int j = i & 7;
    int n = (i >> 3) & 255;
    int qq = i >> 11;
    int k = (qq >> 2) * 32 + (qq & 3) * 8 + j;
    ow2p[i] = f2b(ow2[k * 256 + n]);
    float w = qw2[k * 256 + n];
    unsigned short h = f2b(w);
    qw2h[i] = h;
    qw2l[i] = f2b(w - b2f(h));
  }
  if (i < 106496) {
    int j = i & 7;
    int n = (i >> 3) & 255;
    int qq = i >> 11;  // 0..51 = kb*4+quad
    int k = (qq >> 2) * 32 + (qq & 3) * 8 + j;
    float w = (k < 396) ? qw1[k * 256 + n] : 0.f;
    unsigned short h = f2b(w);
    qw1h[i] = h;
    qw1l[i] = f2b(w - b2f(h));
  }
}

// ---------------------------------------------------------------------------
// Kernel 1: r0/r4 ENGINE (512 threads, 8 waves, 2 blocks/CU, dense
// 16-MFMA16-per-kb inner loop, 1-ahead B prefetch, HSTR=272) with ONE
// change: layer-2 wave tiling (M128,N32) -> (M64,N64).
//   8 waves = 2 m-groups (mg=wave>>2, rows mg*64..+63) x 4 n-groups
//   (ng=wave&3, cols ng*64..+63). Each A-fragment feeds 4 MFMAs (was 2):
//   layer-2 A LDS traffic 512KB -> 256KB/block. B L2 traffic 128->256KB
//   (L2 pipe at 19%, headroom). Epilogue: m-group partials combined via a
//   2KB f32 scratch aliased onto the dead xs buffer (LDS size unchanged).
// ---------------------------------------------------------------------------
#define XSTR 40   // xs row stride in shorts (x2B/16B = 5: conflict-free)
#define HSTR 272  // h1 row stride in shorts

__global__ __launch_bounds__(512, 4) void obstacle_kernel(
    const float* __restrict__ obs, const float* __restrict__ obstacles,
    const unsigned short* __restrict__ ow1q,
    const unsigned short* __restrict__ ow2p,
    const float* __restrict__ ob1, const float* __restrict__ ob2,
    unsigned short* __restrict__ poolH, unsigned short* __restrict__ poolL) {
  __shared__ __align__(16) unsigned short xs[128 * XSTR];  // 10240 B
  __shared__ __align__(16) unsigned short h1[128 * HSTR];  // 69632 B
  __shared__ float maskS[128];
  __shared__ unsigned short vehB[32];

  const int b = blockIdx.x;
  const int tid = threadIdx.x;

  if (tid < 18) vehB[tid] = f2b(obs[b * 138 + tid]);
  if (tid < 128) maskS[tid] = obstacles[b * 640 + 512 + tid];
  __syncthreads();

  // Build x rows (2 threads per row, tid<256): [0:18]=veh, [18:22]=obst.
  if (tid < 256) {
    int n = tid >> 1;
    int half = tid & 1;
    unsigned short* wr = &xs[n * XSTR + half * 16];
    if (half == 0) {
      unsigned short r01[16];
#pragma unroll
      for (int k = 0; k < 16; k++) r01[k] = vehB[k];
      *(short8*)(wr + 0) = *(short8*)&r01[0];
      *(short8*)(wr + 8) = *(short8*)&r01[8];
    } else {
      unsigned short r2[8];
      r2[0] = vehB[16];
      r2[1] = vehB[17];
#pragma unroll
      for (int d = 0; d < 4; d++)
        r2[2 + d] = f2b(obstacles[b * 640 + d * 128 + n]);
      r2[6] = 0; r2[7] = 0;
      *(short8*)(wr + 0) = *(short8*)&r2[0];
      short8 z = {0, 0, 0, 0, 0, 0, 0, 0};
      *(short8*)(wr + 8) = z;
    }
  }
  __syncthreads();

  const int wave = tid >> 6;   // 0..7
  const int lane = tid & 63;
  const int quad = lane >> 4;
  const int l15 = lane & 15;

  // ---- Layer 1 (swapped, D = W1^T x X^T): wave owns 2 n_out tiles
  //      (wave*2, wave*2+1), all 8 row tiles. Bias in C-init. (unchanged) ----
  {
    const unsigned short* wp = &ow1q[wave * 1024 + quad * 128 + l15 * 8];
    short8 wfr[2];
#pragma unroll
    for (int i = 0; i < 2; i++) wfr[i] = *(const short8*)(wp + i * 512);

    const unsigned short* bxp = &xs[l15 * XSTR + quad * 8];
    short8 bx[8];
#pragma unroll
    for (int nt = 0; nt < 8; nt++)
      bx[nt] = *(const short8*)(bxp + nt * 16 * XSTR);

    unsigned short* wrb = &h1[l15 * HSTR + wave * 32 + quad * 4];

#pragma unroll
    for (int i = 0; i < 2; i++) {
      f32x4 cinit = *(const f32x4*)&ob1[wave * 32 + i * 16 + quad * 4];
      f32x4 acc1[8];
#pragma unroll
      for (int nt = 0; nt < 8; nt++) acc1[nt] = MFMA16(wfr[i], bx[nt], cinit);
#pragma unroll
      for (int nt = 0; nt < 8; nt++) {
        float v0 = fmaxf(acc1[nt][0], 0.f);
        float v1 = fmaxf(acc1[nt][1], 0.f);
        float v2 = fmaxf(acc1[nt][2], 0.f);
        float v3 = fmaxf(acc1[nt][3], 0.f);
        uint2 pk;
        pk.x = pk2f(v0, v1);
        pk.y = pk2f(v2, v3);
        *(uint2*)(wrb + nt * 16 * HSTR + i * 16) = pk;
      }
    }
  }
  __syncthreads();

  // ---- Layer 2: (M64,N64). Wave (mg,ng) owns rows mg*64+mt*16 (mt=0..3),
  //      cols ng*64+t*16 (t=0..3). A-frag reuse 4, B-frag reuse 4.
  //      16 MFMA16 per kb per wave (dense body preserved). ----
  const int mg = wave >> 2;    // 0..1
  const int ng = wave & 3;     // 0..3

  f32x4 acc[4][4];             // [mt][t]
#pragma unroll
  for (int t = 0; t < 4; t++) {
    float bv = ob2[ng * 64 + t * 16 + l15];
    f32x4 bvec = {bv, bv, bv, bv};
#pragma unroll
    for (int mt = 0; mt < 4; mt++) acc[mt][t] = bvec;
  }

  const unsigned short* bp = &ow2p[(quad * 256 + ng * 64 + l15) * 8];
  const unsigned short* h1r = &h1[(mg * 64 + l15) * HSTR + quad * 8];
  short8 bcur[4], bnxt[4];
#pragma unroll
  for (int t = 0; t < 4; t++) bcur[t] = *(const short8*)(bp + t * 128);

#pragma unroll 1
  for (int kb = 0; kb < 8; kb++) {
    if (kb < 7) {
#pragma unroll
      for (int t = 0; t < 4; t++)
        bnxt[t] = *(const short8*)(bp + 8192 + t * 128);
    }
    short8 afr[4];
#pragma unroll
    for (int mt = 0; mt < 4; mt++)
      afr[mt] = *(const short8*)(h1r + mt * 16 * HSTR);
#pragma unroll
    for (int mt = 0; mt < 4; mt++)
#pragma unroll
      for (int t = 0; t < 4; t++) acc[mt][t] = MFMA16(afr[mt], bcur[t], acc[mt][t]);
    bp += 8192;
    h1r += 32;
    if (kb < 7) {
#pragma unroll
      for (int t = 0; t < 4; t++) bcur[t] = bnxt[t];
    }
  }

  // ---- Pool epilogue: pooled[n] = sum_m mask[m]*relu(h2[m][n]).
  //      Per wave: sum over its 64 rows (shfl over quads); the two
  //      m-groups' partials combine via poolP (aliases dead xs). ----
  float* poolP = (float*)xs;   // 2*256 f32 = 2048 B <= 10240 B; xs is dead
  f32x4 mk[4];
  const float* mkp = &maskS[mg * 64 + quad * 4];
#pragma unroll
  for (int mt = 0; mt < 4; mt++) mk[mt] = *(const f32x4*)(mkp + mt * 16);

#pragma unroll
  for (int t = 0; t < 4; t++) {
    float s = 0.f;
#pragma unroll
    for (int mt = 0; mt < 4; mt++) {
#pragma unroll
      for (int r = 0; r < 4; r++) {
        float v = fmaxf(acc[mt][t][r], 0.f);
        s = fmaf(mk[mt][r], v, s);
      }
    }
    s += __shfl_xor(s, 16);
    s += __shfl_xor(s, 32);
    if (quad == 0) poolP[mg * 256 + ng * 64 + t * 16 + l15] = s;
  }
  __syncthreads();
  if (tid < 256) {
    float s = poolP[tid] + poolP[256 + tid];
    unsigned short sh = (unsigned short)(__builtin_bit_cast(unsigned, s) >> 16);
    poolH[b * 256 + tid] = sh;  // truncated hi; lo captures remainder
    poolL[b * 256 + tid] = f2b(s - b2f(sh));
  }
}

// ---------------------------------------------------------------------------
// Kernel 2: head MLP (byte-identical to the 166.2us-measured config:
// 256 blocks x 1024 threads, unroll-1 loops, HSTRQ=264).
// ---------------------------------------------------------------------------
__global__ __launch_bounds__(1024) void head_mfma(
    const float* __restrict__ obs, const float* __restrict__ act,
    const unsigned short* __restrict__ poolH,
    const unsigned short* __restrict__ poolL,
    const unsigned short* __restrict__ qw1h,
    const unsigned short* __restrict__ qw1l,
    const unsigned short* __restrict__ qw2h,
    const unsigned short* __restrict__ qw2l,
    const float* __restrict__ qb1, const float* __restrict__ qb2,
    const float* __restrict__ qw3, const float* __restrict__ qb3,
    float* __restrict__ out) {
  const int CSTR = 424;
  const int HSTRQ = 264;
  __shared__ unsigned short combH[16 * 424], combL[16 * 424];
  __shared__ unsigned short h1H[16 * 264], h1L[16 * 264];
  __shared__ float wred[16][16];

  const int tid = threadIdx.x;
  const int r0 = blockIdx.x * 16;

  // Build comb hi/lo: [obs(138) | pooled(256) | act(2) | pad->416]
  for (int idx = tid; idx < 16 * 416; idx += 1024) {
    int m = idx / 416;
    int k = idx - m * 416;
    unsigned short hi, lo;
    if (k < 138) {
      float v = obs[(r0 + m) * 138 + k];
      hi = f2b(v);
      lo = f2b(v - b2f(hi));
    } else if (k < 394) {
      hi = poolH[(r0 + m) * 256 + (k - 138)];
      lo = poolL[(r0 + m) * 256 + (k - 138)];
    } else if (k < 396) {
      float v = act[(r0 + m) * 2 + (k - 394)];
      hi = f2b(v);
      lo = f2b(v - b2f(hi));
    } else {
      hi = 0; lo = 0;
    }
    combH[m * CSTR + k] = hi;
    combL[m * CSTR + k] = lo;
  }
  __syncthreads();

  const int wave = tid >> 6;  // 0..15 = N-tile
  const int lane = tid & 63;
  const int quad = lane >> 4;
  const int l15 = lane & 15;
  const int n = wave * 16 + l15;

  // ---- Layer 1: 13 kb ----
  f32x4 acc = {0.f, 0.f, 0.f, 0.f}, accm = {0.f, 0.f, 0.f, 0.f};
#pragma unroll 1
  for (int kb = 0; kb < 13; kb++) {
    int ao = l15 * CSTR + kb * 32 + quad * 8;
    short8 ah = *(const short8*)&combH[ao];
    short8 al = *(const short8*)&combL[ao];
    int off = ((kb * 4 + quad) * 256 + n) * 8;
    short8 bh = *(const short8*)&qw1h[off];
    short8 bl = *(const short8*)&qw1l[off];
    acc = MFMA16(ah, bh, acc);
    accm = MFMA16(ah, bl, accm);
    accm = MFMA16(al, bh, accm);
  }
  {
    float bias = qb1[n];
#pragma unroll
    for (int r = 0; r < 4; r++) {
      int m = quad * 4 + r;
      float v = fmaxf(acc[r] + accm[r] + bias, 0.f);
      unsigned short hi = f2b(v);
      h1H[m * HSTRQ + n] = hi;
      h1L[m * HSTRQ + n] = f2b(v - b2f(hi));
    }
  }
  __syncthreads();

  // ---- Layer 2: 8 kb ----
  f32x4 a2 = {0.f, 0.f, 0.f, 0.f}, a2m = {0.f, 0.f, 0.f, 0.f};
#pragma unroll 1
  for (int kb = 0; kb < 8; kb++) {
    int ao = l15 * HSTRQ + kb * 32 + quad * 8;
    short8 ah = *(const short8*)&h1H[ao];
    short8 al = *(const short8*)&h1L[ao];
    int off = ((kb * 4 + quad) * 256 + n) * 8;
    short8 bh = *(const short8*)&qw2h[off];
    short8 bl = *(const short8*)&qw2l[off];
    a2 = MFMA16(ah, bh, a2);
    a2m = MFMA16(ah, bl, a2m);
    a2m = MFMA16(al, bh, a2m);
  }

  // ---- Layer 3: f32 dot with qw3, reduce over the wave's 16 cols ----
  {
    float w3 = qw3[n];
    float qb2n = qb2[n];
#pragma unroll
    for (int r = 0; r < 4; r++) {
      float v = fmaxf(a2[r] + a2m[r] + qb2n, 0.f);
      float s = v * w3;
      s += __shfl_xor(s, 1);
      s += __shfl_xor(s, 2);
      s += __shfl_xor(s, 4);
      s += __shfl_xor(s, 8);
      if (l15 == 0) wred[wave][quad * 4 + r] = s;
    }
  }
  __syncthreads();
  if (tid < 16) {
    float s = qb3[0];
#pragma unroll
    for (int w = 0; w < 16; w++) s += wred[w][tid];
    out[r0 + tid] = s;
  }
}

// ---------------------------------------------------------------------------
extern "C" void kernel_launch(void* const* d_in, const int* in_sizes, int n_in,
                              void* d_out, int out_size, void* d_ws, size_t ws_size,
                              hipStream_t stream) {
  const float* obs       = (const float*)d_in[0];
  const float* obstacles = (const float*)d_in[1];
  const float* act       = (const float*)d_in[2];
  const float* ow1       = (const float*)d_in[3];
  const float* ob1       = (const float*)d_in[4];
  const float* ow2       = (const float*)d_in[5];
  const float* ob2       = (const float*)d_in[6];
  const float* qw1       = (const float*)d_in[7];
  const float* qb1       = (const float*)d_in[8];
  const float* qw2       = (const float*)d_in[9];
  const float* qb2       = (const float*)d_in[10];
  const float* qw3       = (const float*)d_in[11];
  const float* qb3       = (const float*)d_in[12];
  float* out = (float*)d_out;

  unsigned short* ow1q = (unsigned short*)d_ws;   // 8192
  unsigned short* ow2p = ow1q + 8192;             // 65536
  unsigned short* qw1h = ow2p + 65536;            // 106496
  unsigned short* qw1l = qw1h + 106496;           // 106496
  unsigned short* qw2h = qw1l + 106496;           // 65536
  unsigned short* qw2l = qw2h + 65536;            // 65536
  unsigned short* poolH = qw2l + 65536;           // 4096*256
  unsigned short* poolL = poolH + 1048576;        // 4096*256

  pack_weights<<<416, 256, 0, stream>>>(ow1, ow2, qw1, qw2, ow1q, ow2p, qw1h,
                                        qw1l, qw2h, qw2l);
  obstacle_kernel<<<4096, 512, 0, stream>>>(obs, obstacles, ow1q, ow2p, ob1,
                                            ob2, poolH, poolL);
  head_mfma<<<256, 1024, 0, stream>>>(obs, act, poolH, poolL, qw1h, qw1l,
                                      qw2h, qw2l, qb1, qb2, qw3, qb3, out);
}